// Round 1
// baseline (104.858 us; speedup 1.0000x reference)
//
#include <hip/hip_runtime.h>
#include <math.h>

typedef float f32x4 __attribute__((ext_vector_type(4)));
typedef __attribute__((address_space(3))) unsigned int lds_u32;
typedef __attribute__((address_space(1))) const unsigned int glb_u32;

// ---------------------------------------------------------------------------
// Kernel 1: row normalization (8 rows per block, 32 lanes per row) + zero
// unsim/psum/accum. Output: fp8 e4m3 rows PRE-SWIZZLED: 16B chunk c of row r
// stored at chunk (c ^ (r&7)); pass1 stages rows verbatim with async
// global_load_lds and reads with the same swizzle.
__global__ __launch_bounds__(256) void norm_kernel(
    const float* __restrict__ X, unsigned char* __restrict__ Y8,
    float* __restrict__ unsim, float* __restrict__ psum,
    float* __restrict__ accum, float inv_sqrtT) {
  int t = threadIdx.x;
  int row = blockIdx.x * 8 + (t >> 5);
  int l32 = t & 31;
  float4 v = ((const float4*)(X + (size_t)row * 128))[l32];
  float s = v.x * v.x + v.y * v.y + v.z * v.z + v.w * v.w;
  s += __shfl_xor(s, 1);
  s += __shfl_xor(s, 2);
  s += __shfl_xor(s, 4);
  s += __shfl_xor(s, 8);
  s += __shfl_xor(s, 16);
  float inv = inv_sqrtT * rsqrtf(fmaxf(s, 1e-24f));
  int pk = __builtin_amdgcn_cvt_pk_fp8_f32(v.x * inv, v.y * inv, 0, false);
  pk = __builtin_amdgcn_cvt_pk_fp8_f32(v.z * inv, v.w * inv, pk, true);
  int chunk = l32 >> 2;
  int off = ((chunk ^ (row & 7)) << 4) + ((l32 & 3) << 2);
  *(unsigned int*)(Y8 + (size_t)row * 128 + off) = (unsigned)pk;
  if (t < 8) unsim[blockIdx.x * 8 + t] = 0.f;
  else if (t < 16) psum[blockIdx.x * 8 + (t - 8)] = 0.f;
  if (blockIdx.x == 0 && t >= 224 && t < 232) accum[t - 224] = 0.f;
}

// ---------------------------------------------------------------------------
// Kernel 2 (R21->R22 restructure): fp8 MFMA similarity pass over
// upper-triangular 128x128 tile pairs.
//
// R22 CHANGE vs the frozen R19/R20 kernel: 256 threads (4 waves), each wave
// owns a full 32x128 stripe (64 elems/thread, acc[2][8]) instead of 512
// threads / 8 waves x 32x64 (32 elems/thread). Rationale from counters:
// VALUBusy 24% = 25.7K cyc/SIMD of which ~70% is PER-WAVE FIXED cost
// (addressing, label loads, reduce trees, flush) -- halving the wave count
// (16640 -> 8320) halves that term while MFMA work per tile is unchanged.
// Bonus: each row is now owned by exactly one wave, so the row-sum flush is
// a plain LDS store (was atomicAdd with 2 contributors).
// Same swizzled-fp8 layout, staging, rare-path algebra and decode -- bitwise
// identical numerics. NO __threadfence (R17/R18: +33 us over 2080 blocks).
__global__ __launch_bounds__(256, 4) void pass1_kernel(
    const unsigned char* __restrict__ Y8, const int* __restrict__ lab,
    float* __restrict__ unsim, float* __restrict__ psumG,
    float* __restrict__ accum, int nt) {
  __shared__ unsigned char As[128][128];  // chunk c at (c ^ (row&7)) * 16
  __shared__ unsigned char Bs[128][128];
  __shared__ int labR[128], labC[128];
  __shared__ float tsumS[128], tcolS[128];
  __shared__ float psumS[256];  // [0:128) rows, [128:256) cols
  __shared__ float diagS[128];
  __shared__ float sS[4];

  // decode linear block id -> (bi, bj), bi <= bj (triangular)
  int b = blockIdx.x;
  float ntf = (float)nt;
  int bi = (int)((2.f * ntf + 1.f -
                  sqrtf((2.f * ntf + 1.f) * (2.f * ntf + 1.f) - 8.f * (float)b)) *
                 0.5f);
  if (bi < 0) bi = 0;
  while ((bi + 1) * nt - ((bi + 1) * bi) / 2 <= b) ++bi;
  while (bi * nt - (bi * (bi - 1)) / 2 > b) --bi;
  int bj = bi + (b - (bi * nt - (bi * (bi - 1)) / 2));
  const int i0 = bi * 128, j0 = bj * 128;
  const bool offdiag = (bi != bj);

  const int t = threadIdx.x;
  const int w = t >> 6, lane = t & 63;

  // ---- async staging: 4 x (A,B) 1KB segments per wave (4 waves) ----
#pragma unroll
  for (int k = 0; k < 4; ++k) {
    const int c0 = w * 64 + k * 256;  // wave-uniform 16B-chunk index
    const int c = c0 + lane;
    __builtin_amdgcn_global_load_lds(
        (glb_u32*)(Y8 + (size_t)i0 * 128 + (size_t)c * 16),
        (lds_u32*)((unsigned char*)&As[0][0] + c0 * 16), 16, 0, 0);
    __builtin_amdgcn_global_load_lds(
        (glb_u32*)(Y8 + (size_t)j0 * 128 + (size_t)c * 16),
        (lds_u32*)((unsigned char*)&Bs[0][0] + c0 * 16), 16, 0, 0);
  }
  if (t < 128) {
    labR[t] = lab[i0 + t];
    tsumS[t] = 0.f;
    psumS[t] = 0.f;
    diagS[t] = 0.f;
  } else {
    labC[t - 128] = lab[j0 + t - 128];
    tcolS[t - 128] = 0.f;
    psumS[t] = 0.f;
  }
  __syncthreads();  // drains vmcnt (global_load_lds) + lgkmcnt

  const int quad = lane >> 4, l16 = lane & 15;
  const int rbase = w * 32;  // wave owns rows [rbase, rbase+32), ALL 128 cols
  const int sw = l16 & 7;

  f32x4 acc[2][8] = {};
#pragma unroll
  for (int ks = 0; ks < 4; ++ks) {
    const int ch = ks * 2 + (quad >> 1);
    const int off = ((ch ^ sw) << 4) + ((quad & 1) << 3);
    long af[2], bf[8];
#pragma unroll
    for (int p = 0; p < 2; ++p)
      af[p] = *(const long*)&As[rbase + p * 16 + l16][off];
#pragma unroll
    for (int p = 0; p < 8; ++p)
      bf[p] = *(const long*)&Bs[p * 16 + l16][off];
#pragma unroll
    for (int pi = 0; pi < 2; ++pi)
#pragma unroll
      for (int pj = 0; pj < 8; ++pj)
        acc[pi][pj] = __builtin_amdgcn_mfma_f32_16x16x32_fp8_fp8(
            af[pi], bf[pj], acc[pi][pj], 0, 0, 0);
  }

  // ---- epilogue: branch-free totals + rare positive/diag path ----
  int lr[2][4], lc[8];
#pragma unroll
  for (int pi = 0; pi < 2; ++pi)
#pragma unroll
    for (int r = 0; r < 4; ++r) lr[pi][r] = labR[rbase + pi * 16 + quad * 4 + r];
#pragma unroll
  for (int pj = 0; pj < 8; ++pj) lc[pj] = labC[pj * 16 + l16];

  float trow[2][4] = {};
  float tcol[8] = {};
  float sacc = 0.f;
#pragma unroll
  for (int pi = 0; pi < 2; ++pi)
#pragma unroll
    for (int pj = 0; pj < 8; ++pj)
#pragma unroll
      for (int r = 0; r < 4; ++r) {
        const float s = acc[pi][pj][r];
        const float e = __expf(s);
        trow[pi][r] += e;
        tcol[pj] += e;
        if (lr[pi][r] == lc[pj]) {  // rare: 1/128
          const int row = rbase + pi * 16 + quad * 4 + r;
          const int col = pj * 16 + l16;
          if (offdiag) {
            atomicAdd(&psumS[row], e);
            atomicAdd(&psumS[128 + col], e);
            sacc += 2.f * s;
          } else if (row != col) {
            atomicAdd(&psumS[row], e);
            sacc += s;
          } else {
            diagS[row] = e;  // unique writer
          }
        }
      }

  // row sums: 4-shfl reduce over 16 cols; each row has a UNIQUE owner wave
  // -> plain store (no atomic needed, R22)
#pragma unroll
  for (int pi = 0; pi < 2; ++pi)
#pragma unroll
    for (int r = 0; r < 4; ++r) {
      float v = trow[pi][r];
      v += __shfl_xor(v, 1);
      v += __shfl_xor(v, 2);
      v += __shfl_xor(v, 4);
      v += __shfl_xor(v, 8);
      if (l16 == 0) tsumS[rbase + pi * 16 + quad * 4 + r] = v;
    }
  // col sums: reduce across quads (each wave contributes its 32-row stripe)
#pragma unroll
  for (int pj = 0; pj < 8; ++pj) {
    float v = tcol[pj];
    v += __shfl_xor(v, 16);
    v += __shfl_xor(v, 32);
    if (quad == 0) atomicAdd(&tcolS[pj * 16 + l16], v);
  }
  // block scalar: sum_pos s
#pragma unroll
  for (int m = 1; m < 64; m <<= 1) sacc += __shfl_xor(sacc, m);
  if (lane == 0) sS[w] = sacc;
  __syncthreads();

  // flush: unsim += t - diag (so unsim = u + p), psum += p; one scalar atomic
  if (t < 128) {
    atomicAdd(&unsim[i0 + t], tsumS[t] - diagS[t]);
    atomicAdd(&psumG[i0 + t], psumS[t]);
  } else if (offdiag) {  // t in [128,256)
    atomicAdd(&unsim[j0 + (t - 128)], tcolS[t - 128]);
    atomicAdd(&psumG[j0 + (t - 128)], psumS[t]);
  }
  if (t == 0) {
    atomicAdd(&accum[4], sS[0] + sS[1] + sS[2] + sS[3]);
  }
}

// ---------------------------------------------------------------------------
// Kernel 3: finalize (one 1024-thread block — 8 serial L2 iterations/thread):
//   loss_sum = sum_i [cnt_i*log(u_i) + p_i/u_i] - ssum,  u = unsim - p
//   n_pos    = sum_c m_c^2 - N;   out = loss_sum / n_pos
__global__ __launch_bounds__(1024) void finalize_kernel(
    const int* __restrict__ lab, const float* __restrict__ unsim,
    const float* __restrict__ psum, const float* __restrict__ accum,
    float* __restrict__ out, int N) {
  __shared__ int hist[256];
  __shared__ float redL[16], redN[16];
  int t = threadIdx.x;
  int lane = t & 63, w = t >> 6;
  if (t < 256) hist[t] = 0;
  __syncthreads();
  for (int i = t; i < N; i += 1024) atomicAdd(&hist[lab[i] & 255], 1);
  __syncthreads();
  float local = 0.f;
  for (int i = t; i < N; i += 1024) {
    float tot = unsim[i];
    float p = psum[i];
    float u = tot - p;
    float c = (float)(hist[lab[i] & 255] - 1);
    local += c * __logf(u) + p / u;
  }
  float nposl = 0.f;
  if (t < 256) {
    float m = (float)hist[t];
    nposl = m * m;
  }
#pragma unroll
  for (int msk = 1; msk < 64; msk <<= 1) {
    local += __shfl_xor(local, msk);
    nposl += __shfl_xor(nposl, msk);
  }
  if (lane == 0) {
    redL[w] = local;
    redN[w] = nposl;
  }
  __syncthreads();
  if (t == 0) {
    float ls = 0.f, np = 0.f;
#pragma unroll
    for (int i = 0; i < 16; ++i) {
      ls += redL[i];
      np += redN[i];
    }
    out[0] = (ls - accum[4]) / (np - (float)N);
  }
}

// ---------------------------------------------------------------------------
extern "C" void kernel_launch(void* const* d_in, const int* in_sizes, int n_in,
                              void* d_out, int out_size, void* d_ws,
                              size_t ws_size, hipStream_t stream) {
  const float* X = (const float*)d_in[0];
  const int* lab = (const int*)d_in[1];
  float* out = (float*)d_out;

  const int N = in_sizes[1];  // 8192; D fixed at 128

  // workspace layout
  unsigned char* Y8 = (unsigned char*)d_ws;       // N*128 fp8 (1 MB)
  float* unsim = (float*)(Y8 + (size_t)N * 128);  // N f32 (= u + p)
  float* psum = unsim + N;                        // N f32
  float* accum = psum + N;                        // [4] ssum

  const float inv_sqrtT = 2.2360679775f;  // 1/sqrt(0.2)
  norm_kernel<<<N / 8, 256, 0, stream>>>(X, Y8, unsim, psum, accum,
                                         inv_sqrtT);

  const int nt = N / 128;              // 64 tiles per dim
  const int nblk = nt * (nt + 1) / 2;  // 2080 upper-tri tile pairs
  pass1_kernel<<<nblk, 256, 0, stream>>>(Y8, lab, unsim, psum, accum, nt);
  finalize_kernel<<<1, 1024, 0, stream>>>(lab, unsim, psum, accum, out, N);
}

// Round 2
// 98.471 us; speedup vs baseline: 1.0649x; 1.0649x over previous
//
#include <hip/hip_runtime.h>
#include <math.h>

typedef float f32x4 __attribute__((ext_vector_type(4)));
typedef __attribute__((address_space(3))) unsigned int lds_u32;
typedef __attribute__((address_space(1))) const unsigned int glb_u32;

// ---------------------------------------------------------------------------
// Kernel 1: row normalization (8 rows per block, 32 lanes per row).
// Output: fp8 e4m3 rows PRE-SWIZZLED: 16B chunk c of row r stored at chunk
// (c ^ (r&7)); pass1 stages rows verbatim with async global_load_lds and
// reads with the same swizzle. (R23: zeroing tail removed — pass1 now uses
// write-once partial arrays, nothing needs pre-zeroing.)
__global__ __launch_bounds__(256) void norm_kernel(
    const float* __restrict__ X, unsigned char* __restrict__ Y8,
    float inv_sqrtT) {
  int t = threadIdx.x;
  int row = blockIdx.x * 8 + (t >> 5);
  int l32 = t & 31;
  float4 v = ((const float4*)(X + (size_t)row * 128))[l32];
  float s = v.x * v.x + v.y * v.y + v.z * v.z + v.w * v.w;
  s += __shfl_xor(s, 1);
  s += __shfl_xor(s, 2);
  s += __shfl_xor(s, 4);
  s += __shfl_xor(s, 8);
  s += __shfl_xor(s, 16);
  float inv = inv_sqrtT * rsqrtf(fmaxf(s, 1e-24f));
  int pk = __builtin_amdgcn_cvt_pk_fp8_f32(v.x * inv, v.y * inv, 0, false);
  pk = __builtin_amdgcn_cvt_pk_fp8_f32(v.z * inv, v.w * inv, pk, true);
  int chunk = l32 >> 2;
  int off = ((chunk ^ (row & 7)) << 4) + ((l32 & 3) << 2);
  *(unsigned int*)(Y8 + (size_t)row * 128 + off) = (unsigned)pk;
}

// ---------------------------------------------------------------------------
// Kernel 2 (R23 restructure — kill the global atomics): full-matrix
// row-panel chunks instead of triangular tile pairs.
//
// WHY (R22 counters): pass1's WRITE_SIZE was 4161 KB == 2080 blocks x 32
// lines x 64B EXACTLY — every atomicAdd flush line bounced through HBM
// (cross-XCD memory-side RMW), ~2000 serialized RMWs per hot line. That
// serialization, not compute, was the ~45 us floor (R22: halving waves
// changed nothing; R17/R18: __threadfence on this path cost +33 us).
//
// Structure: grid = 64 row-panels x 8 chunks = 512 blocks (2/CU), 256 thr.
// Block (bi,c) computes rows [bi*128,+128) x B-tiles jtile=c*8..c*8+7 of
// the FULL matrix (symmetry dropped: MFMA was 7% utilized, +4 us of busy
// time buys removal of ALL mirror/atomic machinery). A-fragments register-
// resident across all 8 tiles; B double-buffered, staged before compute so
// the barrier vmcnt-drain overlaps the exp epilogue. Row sums accumulate in
// registers; flush is plain coalesced stores into write-once partials
// P/Q[8][8192] + S[512]. Zero global atomics. c==b&7 keeps same-chunk
// blocks on one XCD -> its 8 B-tiles (128KB) stay L2-resident.
__global__ __launch_bounds__(256, 2) void pass1_kernel(
    const unsigned char* __restrict__ Y8, const int* __restrict__ lab,
    float* __restrict__ P, float* __restrict__ Q, float* __restrict__ S,
    int N) {
  __shared__ unsigned char As[128][128];     // chunk cc at (cc ^ (row&7))*16
  __shared__ unsigned char Bs[2][128][128];  // double-buffered B tiles
  __shared__ int labR[128];
  __shared__ float tsumS[128], psumS[128], diagS[128];
  __shared__ float sS[4];

  const int b = blockIdx.x;
  const int bi = b >> 3, c = b & 7;
  const int i0 = bi * 128;
  const int t = threadIdx.x;
  const int w = t >> 6, lane = t & 63;

  // ---- prologue staging: A panel + first B tile (4 x 1KB segs per wave) ----
#pragma unroll
  for (int k = 0; k < 4; ++k) {
    const int c0 = w * 64 + k * 256;  // wave-uniform 16B-chunk index
    const int cc = c0 + lane;
    __builtin_amdgcn_global_load_lds(
        (glb_u32*)(Y8 + (size_t)i0 * 128 + (size_t)cc * 16),
        (lds_u32*)((unsigned char*)&As[0][0] + c0 * 16), 16, 0, 0);
    __builtin_amdgcn_global_load_lds(
        (glb_u32*)(Y8 + (size_t)(c * 8) * 128 * 128 + (size_t)cc * 16),
        (lds_u32*)((unsigned char*)&Bs[0][0][0] + c0 * 16), 16, 0, 0);
  }
  if (t < 128) {
    labR[t] = lab[i0 + t];
    psumS[t] = 0.f;
    diagS[t] = 0.f;
  }
  __syncthreads();  // drains vmcnt (global_load_lds) + lgkmcnt

  const int quad = lane >> 4, l16 = lane & 15;
  const int rbase = w * 32;  // wave owns rows [rbase, rbase+32)
  const int sw = l16 & 7;

  // ---- hoist A fragments: reused across all 8 B tiles ----
  long af[4][2];
#pragma unroll
  for (int ks = 0; ks < 4; ++ks) {
    const int ch = ks * 2 + (quad >> 1);
    const int off = ((ch ^ sw) << 4) + ((quad & 1) << 3);
#pragma unroll
    for (int p = 0; p < 2; ++p)
      af[ks][p] = *(const long*)&As[rbase + p * 16 + l16][off];
  }
  int lr[2][4];
#pragma unroll
  for (int pi = 0; pi < 2; ++pi)
#pragma unroll
    for (int r = 0; r < 4; ++r)
      lr[pi][r] = labR[rbase + pi * 16 + quad * 4 + r];

  float trow[2][4] = {};  // row exp-sums, accumulated across all 8 tiles
  float sacc = 0.f;       // sum of s over positive (label-match, offdiag)

#pragma unroll 2
  for (int jt = 0; jt < 8; ++jt) {
    const int cur = jt & 1;
    const int jtile = c * 8 + jt;
    const int jt0 = jtile * 128;

    // stage NEXT B tile into the other buffer; its vmcnt drain happens at
    // this iteration's end-barrier, i.e. overlapped with MFMA + epilogue
    if (jt < 7) {
      const unsigned char* src = Y8 + (size_t)(jt0 + 128) * 128;
      unsigned char* dst = (unsigned char*)&Bs[cur ^ 1][0][0];
#pragma unroll
      for (int k = 0; k < 4; ++k) {
        const int c0 = w * 64 + k * 256;
        const int cc = c0 + lane;
        __builtin_amdgcn_global_load_lds((glb_u32*)(src + (size_t)cc * 16),
                                         (lds_u32*)(dst + c0 * 16), 16, 0, 0);
      }
    }

    // column labels for this tile (L2-resident, latency hidden by MFMA)
    int lc[8];
#pragma unroll
    for (int pj = 0; pj < 8; ++pj) lc[pj] = lab[jt0 + pj * 16 + l16];

    f32x4 acc[2][8] = {};
#pragma unroll
    for (int ks = 0; ks < 4; ++ks) {
      const int ch = ks * 2 + (quad >> 1);
      const int off = ((ch ^ sw) << 4) + ((quad & 1) << 3);
      long bf[8];
#pragma unroll
      for (int p = 0; p < 8; ++p)
        bf[p] = *(const long*)&Bs[cur][p * 16 + l16][off];
#pragma unroll
      for (int pi = 0; pi < 2; ++pi)
#pragma unroll
        for (int pj = 0; pj < 8; ++pj)
          acc[pi][pj] = __builtin_amdgcn_mfma_f32_16x16x32_fp8_fp8(
              af[ks][pi], bf[pj], acc[pi][pj], 0, 0, 0);
    }

    // epilogue: branch-free totals + rare positive/diag path (1/128)
    const bool dtile = (jtile == bi);
#pragma unroll
    for (int pi = 0; pi < 2; ++pi)
#pragma unroll
      for (int pj = 0; pj < 8; ++pj)
#pragma unroll
        for (int r = 0; r < 4; ++r) {
          const float s = acc[pi][pj][r];
          const float e = __expf(s);
          trow[pi][r] += e;
          if (lr[pi][r] == lc[pj]) {
            const int rowl = rbase + pi * 16 + quad * 4 + r;
            const int cl = pj * 16 + l16;
            if (dtile && rowl == cl) {
              diagS[rowl] = e;  // unique writer
            } else {
              atomicAdd(&psumS[rowl], e);  // LDS only, rare
              sacc += s;  // each ordered pair visited exactly once
            }
          }
        }
    __syncthreads();  // buffer handoff + drains next-tile staging
  }

  // row totals -> tsumS; each row has a unique owner wave (plain store)
#pragma unroll
  for (int pi = 0; pi < 2; ++pi)
#pragma unroll
    for (int r = 0; r < 4; ++r) {
      float v = trow[pi][r];
      v += __shfl_xor(v, 1);
      v += __shfl_xor(v, 2);
      v += __shfl_xor(v, 4);
      v += __shfl_xor(v, 8);
      if (l16 == 0) tsumS[rbase + pi * 16 + quad * 4 + r] = v;
    }
#pragma unroll
  for (int m = 1; m < 64; m <<= 1) sacc += __shfl_xor(sacc, m);
  if (lane == 0) sS[w] = sacc;
  __syncthreads();

  // flush: ONE write-once partial slot per (chunk,row). No atomics.
  if (t < 128) {
    const int gi = i0 + t;
    P[c * N + gi] = tsumS[t] - diagS[t];  // = (u + p) partial for this chunk
    Q[c * N + gi] = psumS[t];
  }
  if (t == 0) S[b] = sS[0] + sS[1] + sS[2] + sS[3];
}

// ---------------------------------------------------------------------------
// Kernel 3: finalize (one 1024-thread block):
//   per row: tot = sum_c P[c][i], p = sum_c Q[c][i], u = tot - p
//   loss_sum = sum_i [cnt_i*log(u_i) + p_i/u_i] - sum(S),
//   n_pos = sum_c m_c^2 - N;  out = loss_sum / n_pos
__global__ __launch_bounds__(1024) void finalize_kernel(
    const int* __restrict__ lab, const float* __restrict__ P,
    const float* __restrict__ Q, const float* __restrict__ S,
    float* __restrict__ out, int N) {
  __shared__ int hist[256];
  __shared__ float redL[16], redN[16], redS[16];
  int t = threadIdx.x;
  int lane = t & 63, w = t >> 6;
  if (t < 256) hist[t] = 0;
  __syncthreads();
  for (int i = t; i < N; i += 1024) atomicAdd(&hist[lab[i] & 255], 1);
  __syncthreads();
  float local = 0.f;
  for (int i = t; i < N; i += 1024) {
    float tot = 0.f, p = 0.f;
#pragma unroll
    for (int cc = 0; cc < 8; ++cc) {
      tot += P[cc * N + i];
      p += Q[cc * N + i];
    }
    float u = tot - p;
    float cnt = (float)(hist[lab[i] & 255] - 1);
    local += cnt * __logf(u) + p / u;
  }
  float nposl = 0.f;
  if (t < 256) {
    float m = (float)hist[t];
    nposl = m * m;
  }
  float sl = (t < 512) ? S[t] : 0.f;
#pragma unroll
  for (int msk = 1; msk < 64; msk <<= 1) {
    local += __shfl_xor(local, msk);
    nposl += __shfl_xor(nposl, msk);
    sl += __shfl_xor(sl, msk);
  }
  if (lane == 0) {
    redL[w] = local;
    redN[w] = nposl;
    redS[w] = sl;
  }
  __syncthreads();
  if (t == 0) {
    float ls = 0.f, np = 0.f, ss = 0.f;
#pragma unroll
    for (int i = 0; i < 16; ++i) {
      ls += redL[i];
      np += redN[i];
      ss += redS[i];
    }
    out[0] = (ls - ss) / (np - (float)N);
  }
}

// ---------------------------------------------------------------------------
extern "C" void kernel_launch(void* const* d_in, const int* in_sizes, int n_in,
                              void* d_out, int out_size, void* d_ws,
                              size_t ws_size, hipStream_t stream) {
  const float* X = (const float*)d_in[0];
  const int* lab = (const int*)d_in[1];
  float* out = (float*)d_out;

  const int N = in_sizes[1];  // 8192; D fixed at 128

  // workspace layout: Y8 (1MB) | P[8][N] (256KB) | Q[8][N] (256KB) | S[512]
  unsigned char* Y8 = (unsigned char*)d_ws;
  float* P = (float*)(Y8 + (size_t)N * 128);
  float* Q = P + 8 * (size_t)N;
  float* S = Q + 8 * (size_t)N;

  const float inv_sqrtT = 2.2360679775f;  // 1/sqrt(0.2)
  norm_kernel<<<N / 8, 256, 0, stream>>>(X, Y8, inv_sqrtT);

  const int nblk = (N / 128) * 8;  // 64 row-panels x 8 chunks = 512
  pass1_kernel<<<nblk, 256, 0, stream>>>(Y8, lab, P, Q, S, N);
  finalize_kernel<<<1, 1024, 0, stream>>>(lab, P, Q, S, out, N);
}

// Round 4
// 98.395 us; speedup vs baseline: 1.0657x; 1.0008x over previous
//
#include <hip/hip_runtime.h>
#include <math.h>

typedef float f32x4 __attribute__((ext_vector_type(4)));
typedef __attribute__((address_space(3))) unsigned int lds_u32;
typedef __attribute__((address_space(1))) const unsigned int glb_u32;

// ---------------------------------------------------------------------------
// Kernel 1: row normalization (8 rows per block, 32 lanes per row).
// Output: fp8 e4m3 rows PRE-SWIZZLED: 16B chunk c of row r stored at chunk
// (c ^ (r&7)); pass1 stages rows verbatim with async global_load_lds and
// reads with the same swizzle. Also zeroes out[0] (finalize accumulates into
// it atomically; stream order: fill-poison -> norm -> pass1 -> finalize).
__global__ __launch_bounds__(256) void norm_kernel(
    const float* __restrict__ X, unsigned char* __restrict__ Y8,
    float* __restrict__ out, float inv_sqrtT) {
  int t = threadIdx.x;
  int row = blockIdx.x * 8 + (t >> 5);
  int l32 = t & 31;
  float4 v = ((const float4*)(X + (size_t)row * 128))[l32];
  float s = v.x * v.x + v.y * v.y + v.z * v.z + v.w * v.w;
  s += __shfl_xor(s, 1);
  s += __shfl_xor(s, 2);
  s += __shfl_xor(s, 4);
  s += __shfl_xor(s, 8);
  s += __shfl_xor(s, 16);
  float inv = inv_sqrtT * rsqrtf(fmaxf(s, 1e-24f));
  int pk = __builtin_amdgcn_cvt_pk_fp8_f32(v.x * inv, v.y * inv, 0, false);
  pk = __builtin_amdgcn_cvt_pk_fp8_f32(v.z * inv, v.w * inv, pk, true);
  int chunk = l32 >> 2;
  int off = ((chunk ^ (row & 7)) << 4) + ((l32 & 3) << 2);
  *(unsigned int*)(Y8 + (size_t)row * 128 + off) = (unsigned)pk;
  if (blockIdx.x == 0 && t == 0) out[0] = 0.f;
}

// ---------------------------------------------------------------------------
// Kernel 2 (R24/R25): full-matrix row-panel x chunk, occupancy-first.
//
// R23 post-mortem: atomic-free partials were right (pathological WRITE_SIZE
// gone) but pass1 stayed ~40us. Suspect: 512 blocks = 2 blocks/CU = 2
// waves/SIMD -- nothing to hide the 8 per-phase vmcnt-drain barriers or the
// quarter-rate v_exp chains; plus 64 unrolled exec-mask branches per tile.
//
// R24: grid = 64 panels x 16 chunks = 1024 blocks (4/CU), LDS 33KB
// (Bs = 2 x 64x128 half-tiles, 8 phases of 64 cols). Epilogue is fully
// BRANCH-FREE: trow/pr/sacc accumulate in registers via cndmask selects;
// no LDS atomics, no psumS/diagS. Diagonal phases take a wave-uniform
// variant that excludes self-pairs. A-fragments re-read from LDS per phase
// (trades 8 ds_read_b64/phase for ~16 VGPRs to stay under the 128 cap).
__global__ __launch_bounds__(256, 4) void pass1_kernel(
    const unsigned char* __restrict__ Y8, const int* __restrict__ lab,
    float* __restrict__ P, float* __restrict__ Q, float* __restrict__ S,
    int N) {
  __shared__ unsigned char As[128][128];     // chunk cc at (cc ^ (row&7))*16
  __shared__ unsigned char Bs[2][64][128];   // double-buffered 64-col halves
  __shared__ int labR[128];
  __shared__ float sS[4];

  const int b = blockIdx.x;
  const int bi = b >> 4, c = b & 15;  // 64 row-panels x 16 col-chunks
  const int i0 = bi * 128;
  const int j0 = c * 512;  // this block covers cols [j0, j0+512)
  const int t = threadIdx.x;
  const int w = t >> 6, lane = t & 63;

  // ---- prologue staging: A panel (16KB) + first B half-tile (8KB) ----
#pragma unroll
  for (int k = 0; k < 4; ++k) {
    const int c0 = w * 64 + k * 256;  // wave-uniform 16B-chunk index
    const int cc = c0 + lane;
    __builtin_amdgcn_global_load_lds(
        (glb_u32*)(Y8 + (size_t)i0 * 128 + (size_t)cc * 16),
        (lds_u32*)((unsigned char*)&As[0][0] + c0 * 16), 16, 0, 0);
  }
#pragma unroll
  for (int k = 0; k < 2; ++k) {
    const int c0 = w * 64 + k * 256;
    const int cc = c0 + lane;
    __builtin_amdgcn_global_load_lds(
        (glb_u32*)(Y8 + (size_t)j0 * 128 + (size_t)cc * 16),
        (lds_u32*)((unsigned char*)&Bs[0][0][0] + c0 * 16), 16, 0, 0);
  }
  if (t < 128) labR[t] = lab[i0 + t];
  __syncthreads();  // drains vmcnt (global_load_lds) + lgkmcnt

  const int quad = lane >> 4, l16 = lane & 15;
  const int rbase = w * 32;  // wave owns rows [rbase, rbase+32)
  const int sw = l16 & 7;

  int lr[2][4];
#pragma unroll
  for (int pi = 0; pi < 2; ++pi)
#pragma unroll
    for (int r = 0; r < 4; ++r)
      lr[pi][r] = labR[rbase + pi * 16 + quad * 4 + r];

  float trow[2][4] = {};  // row exp-sums (diag excluded), all 8 phases
  float pr[2][4] = {};    // row positive exp-sums
  float sacc = 0.f;       // sum of s over positive (label-match, non-self)

  for (int jt = 0; jt < 8; ++jt) {
    const int cur = jt & 1;
    const int jt0 = j0 + jt * 64;

    // prefetch next half-tile into the other buffer; its vmcnt drain lands
    // at this phase's end-barrier, overlapped with MFMA + epilogue
    if (jt < 7) {
      const unsigned char* src = Y8 + (size_t)(jt0 + 64) * 128;
      unsigned char* dst = (unsigned char*)&Bs[cur ^ 1][0][0];
#pragma unroll
      for (int k = 0; k < 2; ++k) {
        const int c0 = w * 64 + k * 256;
        const int cc = c0 + lane;
        __builtin_amdgcn_global_load_lds((glb_u32*)(src + (size_t)cc * 16),
                                         (lds_u32*)(dst + c0 * 16), 16, 0, 0);
      }
    }

    // column labels + global col index (L2-resident; hidden by MFMA)
    int lc[4], cg[4];
#pragma unroll
    for (int pj = 0; pj < 4; ++pj) {
      cg[pj] = jt0 + pj * 16 + l16;
      lc[pj] = lab[cg[pj]];
    }

    f32x4 acc[2][4] = {};
#pragma unroll
    for (int ks = 0; ks < 4; ++ks) {
      const int ch = ks * 2 + (quad >> 1);
      const int off = ((ch ^ sw) << 4) + ((quad & 1) << 3);
      long af[2], bf[4];
#pragma unroll
      for (int p = 0; p < 2; ++p)
        af[p] = *(const long*)&As[rbase + p * 16 + l16][off];
#pragma unroll
      for (int p = 0; p < 4; ++p)
        bf[p] = *(const long*)&Bs[cur][p * 16 + l16][off];
#pragma unroll
      for (int pi = 0; pi < 2; ++pi)
#pragma unroll
        for (int pj = 0; pj < 4; ++pj)
          acc[pi][pj] = __builtin_amdgcn_mfma_f32_16x16x32_fp8_fp8(
              af[pi], bf[pj], acc[pi][pj], 0, 0, 0);
    }

    // ---- branch-free epilogue: register-only accumulation ----
    const bool dphase = ((jt0 >> 7) == bi);  // wave-uniform
    if (dphase) {
#pragma unroll
      for (int pi = 0; pi < 2; ++pi)
#pragma unroll
        for (int pj = 0; pj < 4; ++pj)
#pragma unroll
          for (int r = 0; r < 4; ++r) {
            const float s = acc[pi][pj][r];
            const float e = __expf(s);
            const int rowl = rbase + pi * 16 + quad * 4 + r;
            const bool self = (i0 + rowl) == cg[pj];
            const bool match = (lr[pi][r] == lc[pj]) && !self;
            trow[pi][r] += self ? 0.f : e;
            pr[pi][r] += match ? e : 0.f;
            sacc += match ? s : 0.f;
          }
    } else {
#pragma unroll
      for (int pi = 0; pi < 2; ++pi)
#pragma unroll
        for (int pj = 0; pj < 4; ++pj)
#pragma unroll
          for (int r = 0; r < 4; ++r) {
            const float s = acc[pi][pj][r];
            const float e = __expf(s);
            const bool match = (lr[pi][r] == lc[pj]);
            trow[pi][r] += e;
            pr[pi][r] += match ? e : 0.f;
            sacc += match ? s : 0.f;
          }
    }
    __syncthreads();  // buffer handoff + drains next-phase staging
  }

  // ---- flush: reduce across the 16 col-lanes, store write-once partials ----
#pragma unroll
  for (int pi = 0; pi < 2; ++pi)
#pragma unroll
    for (int r = 0; r < 4; ++r) {
      float v = trow[pi][r], q = pr[pi][r];
      v += __shfl_xor(v, 1);
      q += __shfl_xor(q, 1);
      v += __shfl_xor(v, 2);
      q += __shfl_xor(q, 2);
      v += __shfl_xor(v, 4);
      q += __shfl_xor(q, 4);
      v += __shfl_xor(v, 8);
      q += __shfl_xor(q, 8);
      if (l16 == 0) {
        const int row = rbase + pi * 16 + quad * 4 + r;
        P[c * N + i0 + row] = v;  // (u + p) partial for this chunk
        Q[c * N + i0 + row] = q;  // p partial
      }
    }
#pragma unroll
  for (int m = 1; m < 64; m <<= 1) sacc += __shfl_xor(sacc, m);
  if (lane == 0) sS[w] = sacc;
  __syncthreads();
  if (t == 0) S[b] = sS[0] + sS[1] + sS[2] + sS[3];
}

// ---------------------------------------------------------------------------
// Kernel 3 (R24): parallel finalize — 32 blocks x 256 thr, 256 rows each.
// Each block redundantly builds the label histogram in LDS (32KB read),
// folds the 16 chunk-partials per row, subtracts its S-slice, and adds
// blk/(np - N) into out[0] (one device atomic per block; out zeroed by
// norm). Cross-kernel visibility of P/Q/S is the dispatch-boundary
// release/acquire; no intra-kernel cross-XCD reads of plain stores (G16).
__global__ __launch_bounds__(256) void finalize_kernel(
    const int* __restrict__ lab, const float* __restrict__ P,
    const float* __restrict__ Q, const float* __restrict__ S,
    float* __restrict__ out, int N) {
  __shared__ int hist[256];
  __shared__ float red[4];
  const int b = blockIdx.x, t = threadIdx.x;
  const int lane = t & 63, w = t >> 6;
  hist[t] = 0;
  __syncthreads();
  for (int i = t; i < N; i += 256) atomicAdd(&hist[lab[i] & 255], 1);
  __syncthreads();

  const int i = b * 256 + t;
  float tot = 0.f, p = 0.f;
#pragma unroll
  for (int cc = 0; cc < 16; ++cc) {
    tot += P[cc * N + i];
    p += Q[cc * N + i];
  }
  const float u = tot - p;
  const float cnti = (float)(hist[lab[i] & 255] - 1);
  float local = cnti * __logf(u) + p / u;
  if (t < 32) local -= S[b * 32 + t];  // fold this block's S-slice (32 of 1024)
#pragma unroll
  for (int m = 1; m < 64; m <<= 1) local += __shfl_xor(local, m);
  if (lane == 0) red[w] = local;
  __syncthreads();
  if (t == 0) {
    float np = 0.f;
    for (int k = 0; k < 256; ++k) {
      const float m = (float)hist[k];
      np += m * m;
    }
    atomicAdd(out, (red[0] + red[1] + red[2] + red[3]) / (np - (float)N));
  }
}

// ---------------------------------------------------------------------------
extern "C" void kernel_launch(void* const* d_in, const int* in_sizes, int n_in,
                              void* d_out, int out_size, void* d_ws,
                              size_t ws_size, hipStream_t stream) {
  const float* X = (const float*)d_in[0];
  const int* lab = (const int*)d_in[1];
  float* out = (float*)d_out;

  const int N = in_sizes[1];  // 8192; D fixed at 128

  // workspace: Y8 (1MB) | P[16][N] (512KB) | Q[16][N] (512KB) | S[1024]
  unsigned char* Y8 = (unsigned char*)d_ws;
  float* P = (float*)(Y8 + (size_t)N * 128);
  float* Q = P + 16 * (size_t)N;
  float* S = Q + 16 * (size_t)N;

  const float inv_sqrtT = 2.2360679775f;  // 1/sqrt(0.2)
  norm_kernel<<<N / 8, 256, 0, stream>>>(X, Y8, out, inv_sqrtT);

  const int nblk = (N / 128) * 16;  // 64 panels x 16 chunks = 1024
  pass1_kernel<<<nblk, 256, 0, stream>>>(Y8, lab, P, Q, S, N);
  finalize_kernel<<<N / 256, 256, 0, stream>>>(lab, P, Q, S, out, N);
}